// Round 4
// baseline (776.730 us; speedup 1.0000x reference)
//
#include <hip/hip_runtime.h>
#include <math.h>

#define DD 128
#define SCHUNK 2048

typedef __attribute__((ext_vector_type(8))) short short8;
typedef __attribute__((ext_vector_type(4))) float f32x4;
typedef __attribute__((ext_vector_type(4))) unsigned short us4;

__device__ __forceinline__ unsigned short f2bf(float f) {
  unsigned int u = __builtin_bit_cast(unsigned int, f);
  u = (u + 0x7FFFu + ((u >> 16) & 1u)) >> 16;   // RNE (finite inputs)
  return (unsigned short)u;
}

__device__ __forceinline__ short8 pack8(float4 a, float4 b) {
  short8 r;
  r[0] = (short)f2bf(a.x); r[1] = (short)f2bf(a.y);
  r[2] = (short)f2bf(a.z); r[3] = (short)f2bf(a.w);
  r[4] = (short)f2bf(b.x); r[5] = (short)f2bf(b.y);
  r[6] = (short)f2bf(b.z); r[7] = (short)f2bf(b.w);
  return r;
}

// ---------------------------------------------------------------------------
// Row conversion f32 -> bf16: [A | B] into one table (A first, B after).
// ---------------------------------------------------------------------------
__global__ __launch_bounds__(256) void rowconv_kernel(
    const float* __restrict__ A, const float* __restrict__ B,
    unsigned short* __restrict__ dst, int nA4, int ntot4)
{
  int stride = gridDim.x * 256;
  for (int i = blockIdx.x * 256 + threadIdx.x; i < ntot4; i += stride) {
    float4 v = (i < nA4) ? ((const float4*)A)[i] : ((const float4*)B)[i - nA4];
    us4 o;
    o[0] = f2bf(v.x); o[1] = f2bf(v.y); o[2] = f2bf(v.z); o[3] = f2bf(v.w);
    ((us4*)dst)[i] = o;
  }
}

// ---------------------------------------------------------------------------
// Weight conversion f32 -> bf16: [Wrev | Wfwd | Wgate]
// ---------------------------------------------------------------------------
__global__ __launch_bounds__(256) void wconv_kernel(
    const float* __restrict__ Wrev, const float* __restrict__ Wfwd,
    const float* __restrict__ Wgate, unsigned short* __restrict__ dst)
{
  int i = blockIdx.x * 256 + threadIdx.x;   // 65536 total
  float v;
  if (i < 16384) v = Wrev[i];
  else if (i < 32768) v = Wfwd[i - 16384];
  else v = Wgate[i - 32768];
  dst[i] = f2bf(v);
}

// ---------------------------------------------------------------------------
// Phase 1: degree histogram
// ---------------------------------------------------------------------------
__global__ __launch_bounds__(256) void hist_kernel(
    const int* __restrict__ src, const int* __restrict__ dst,
    int* __restrict__ cnt, int n_a, int E)
{
  int e = blockIdx.x * 256 + threadIdx.x;
  if (e >= E) return;
  atomicAdd(&cnt[src[e]], 1);
  atomicAdd(&cnt[n_a + dst[e]], 1);
}

// ---------------------------------------------------------------------------
// Phase 2: exclusive scan (3 kernels)
// ---------------------------------------------------------------------------
__global__ __launch_bounds__(256) void scan1_kernel(
    const int* __restrict__ cnt, int n, int* __restrict__ partials)
{
  __shared__ int sd[256];
  int t = threadIdx.x;
  int base = blockIdx.x * SCHUNK;
  int s = 0;
  #pragma unroll
  for (int k = 0; k < 8; ++k) {
    int i = base + t * 8 + k;
    s += (i < n) ? cnt[i] : 0;
  }
  sd[t] = s;
  __syncthreads();
  for (int off = 128; off > 0; off >>= 1) {
    if (t < off) sd[t] += sd[t + off];
    __syncthreads();
  }
  if (t == 0) partials[blockIdx.x] = sd[0];
}

__global__ __launch_bounds__(256) void scan2_kernel(int* __restrict__ partials, int nch)
{
  __shared__ int buf[256];
  int t = threadIdx.x;
  int v = (t < nch) ? partials[t] : 0;
  buf[t] = v;
  __syncthreads();
  for (int off = 1; off < 256; off <<= 1) {
    int x = (t >= off) ? buf[t - off] : 0;
    __syncthreads();
    buf[t] += x;
    __syncthreads();
  }
  if (t < nch) partials[t] = buf[t] - v;   // exclusive
}

__global__ __launch_bounds__(256) void scan3_kernel(
    const int* __restrict__ cnt, int n, const int* __restrict__ partials,
    int* __restrict__ start, int* __restrict__ cursor)
{
  __shared__ int sd[256];
  int t = threadIdx.x;
  int base = blockIdx.x * SCHUNK;
  int loc[8];
  int s = 0;
  #pragma unroll
  for (int k = 0; k < 8; ++k) {
    int i = base + t * 8 + k;
    loc[k] = (i < n) ? cnt[i] : 0;
    s += loc[k];
  }
  sd[t] = s;
  __syncthreads();
  for (int off = 1; off < 256; off <<= 1) {
    int x = (t >= off) ? sd[t - off] : 0;
    __syncthreads();
    sd[t] += x;
    __syncthreads();
  }
  int off = partials[blockIdx.x] + sd[t] - s;
  #pragma unroll
  for (int k = 0; k < 8; ++k) {
    int i = base + t * 8 + k;
    if (i < n) { start[i] = off; cursor[i] = off; }
    off += loc[k];
  }
}

// ---------------------------------------------------------------------------
// Phase 3: scatter partner ids
// ---------------------------------------------------------------------------
__global__ __launch_bounds__(256) void scatter_ids_kernel(
    const int* __restrict__ src, const int* __restrict__ dst,
    int* __restrict__ cursor, int* __restrict__ partner, int n_a, int E)
{
  int e = blockIdx.x * 256 + threadIdx.x;
  if (e >= E) return;
  int s = src[e], d = dst[e];
  int p = atomicAdd(&cursor[s], 1);
  partner[p] = d;
  int q = atomicAdd(&cursor[n_a + d], 1);
  partner[q] = s;
}

// ---------------------------------------------------------------------------
// Mega kernel: per wave (16 rows): gather-mean (bf16 partner table) into a
// per-wave LDS patch, then t = mean @ Wr^T + br (masked), relayout t into the
// same patch, gate GEMM (row | t) @ Wg^T + bg, blend, store.
// Weights read directly from global bf16 (L2-resident); LDS = 16 KB/block.
// ---------------------------------------------------------------------------
__global__ __launch_bounds__(256, 3) void mega_kernel(
    const float* __restrict__ rowsT,           // f32 rows of this range
    const unsigned short* __restrict__ tbl_bf, // bf16 rows of OPPOSITE table
    const int* __restrict__ partner,
    const int* __restrict__ start,             // range-local (values global)
    const int* __restrict__ cnt,               // range-local
    const unsigned short* __restrict__ Wr_bf,  // [128][128] bf16
    const unsigned short* __restrict__ Wg_bf,  // [128][256] bf16
    const float* __restrict__ br, const float* __restrict__ bg,
    float* __restrict__ out, int n)
{
  __shared__ unsigned short patch[4][16 * DD];   // 16 KB

  const int t = threadIdx.x;
  const int wid  = t >> 6;
  const int lane = t & 63;
  const int lrow = lane & 15;
  const int lgrp = lane >> 4;
  const int m0 = blockIdx.x * 64 + wid * 16;
  if (m0 >= n) return;
  unsigned short* tw = patch[wid];

  // ---- Phase A: aggregate 16 rows, write bf16 mean into patch -------------
  const int moct = lane >> 2;          // octet of element 2*lane
  const int mei  = (2 * lane) & 7;     // index within octet
  #pragma unroll 1
  for (int i = 0; i < 16; ++i) {
    int r = m0 + i;
    int c = 0, s0 = 0;
    if (r < n) { c = cnt[r]; s0 = start[r]; }
    float ax = 0.f, ay = 0.f;
    int k = 0;
    for (; k + 4 <= c; k += 4) {
      int p0 = partner[s0 + k + 0];
      int p1 = partner[s0 + k + 1];
      int p2 = partner[s0 + k + 2];
      int p3 = partner[s0 + k + 3];
      unsigned v0 = *(const unsigned*)(tbl_bf + (size_t)p0 * DD + 2 * lane);
      unsigned v1 = *(const unsigned*)(tbl_bf + (size_t)p1 * DD + 2 * lane);
      unsigned v2 = *(const unsigned*)(tbl_bf + (size_t)p2 * DD + 2 * lane);
      unsigned v3 = *(const unsigned*)(tbl_bf + (size_t)p3 * DD + 2 * lane);
      ax += __builtin_bit_cast(float, v0 << 16);
      ay += __builtin_bit_cast(float, v0 & 0xFFFF0000u);
      ax += __builtin_bit_cast(float, v1 << 16);
      ay += __builtin_bit_cast(float, v1 & 0xFFFF0000u);
      ax += __builtin_bit_cast(float, v2 << 16);
      ay += __builtin_bit_cast(float, v2 & 0xFFFF0000u);
      ax += __builtin_bit_cast(float, v3 << 16);
      ay += __builtin_bit_cast(float, v3 & 0xFFFF0000u);
    }
    for (; k < c; ++k) {
      int p = partner[s0 + k];
      unsigned v = *(const unsigned*)(tbl_bf + (size_t)p * DD + 2 * lane);
      ax += __builtin_bit_cast(float, v << 16);
      ay += __builtin_bit_cast(float, v & 0xFFFF0000u);
    }
    float inv = (c > 0) ? (1.f / (float)c) : 0.f;
    unsigned pk = (unsigned)f2bf(ax * inv) | ((unsigned)f2bf(ay * inv) << 16);
    *(unsigned*)&tw[i * DD + (((moct ^ i) << 3)) + mei] = pk;
  }

  // ---- Phase B: t-GEMM ----------------------------------------------------
  short8 am[4];
  #pragma unroll
  for (int ks = 0; ks < 4; ++ks) {
    int o = ks * 4 + lgrp;
    am[ks] = *(short8*)&tw[lrow * DD + ((o ^ lrow) << 3)];
  }

  f32x4 tac[8];
  #pragma unroll
  for (int jt = 0; jt < 8; ++jt) {
    float bv = br[jt * 16 + lrow];
    f32x4 c = {bv, bv, bv, bv};
    #pragma unroll
    for (int ks = 0; ks < 4; ++ks) {
      short8 b = *(const short8*)&Wr_bf[(size_t)(jt * 16 + lrow) * 128 +
                                        (ks * 4 + lgrp) * 8];
      c = __builtin_amdgcn_mfma_f32_16x16x32_bf16(am[ks], b, c, 0, 0, 0);
    }
    tac[jt] = c;
  }

  // cnt==0 -> t = 0 (reference: mean_msg exactly 0)
  const int rbase = m0 + lgrp * 4;
  #pragma unroll
  for (int r = 0; r < 4; ++r) {
    int rr = rbase + r;
    int cv = (rr < n) ? cnt[rr] : 0;
    if (cv == 0) {
      #pragma unroll
      for (int jt = 0; jt < 8; ++jt) tac[jt][r] = 0.f;
    }
  }

  // relayout t: C/D layout -> patch (bf16, octet-swizzled)
  #pragma unroll
  for (int jt = 0; jt < 8; ++jt) {
    int col = jt * 16 + lrow;
    int oc = col >> 3, ci = col & 7;
    #pragma unroll
    for (int r = 0; r < 4; ++r) {
      int rr4 = lgrp * 4 + r;
      tw[rr4 * DD + ((oc ^ rr4) << 3) + ci] = f2bf(tac[jt][r]);
    }
  }

  // A-fragments of row (f32 -> bf16)
  const int mr = m0 + lrow;
  const bool rowok = mr < n;
  short8 ar[4];
  #pragma unroll
  for (int ks = 0; ks < 4; ++ks) {
    int k0 = ks * 32 + lgrp * 8;
    float4 u0 = make_float4(0.f, 0.f, 0.f, 0.f), u1 = u0;
    if (rowok) {
      u0 = *(const float4*)(rowsT + (size_t)mr * DD + k0);
      u1 = *(const float4*)(rowsT + (size_t)mr * DD + k0 + 4);
    }
    ar[ks] = pack8(u0, u1);
  }

  // A-fragments of t from patch
  short8 at[4];
  #pragma unroll
  for (int ks = 0; ks < 4; ++ks) {
    int o = ks * 4 + lgrp;
    at[ks] = *(short8*)&tw[lrow * DD + ((o ^ lrow) << 3)];
  }

  // gate GEMM (K=256) + blend + store
  #pragma unroll
  for (int jt = 0; jt < 8; ++jt) {
    float bv = bg[jt * 16 + lrow];
    f32x4 c = {bv, bv, bv, bv};
    #pragma unroll
    for (int ks = 0; ks < 4; ++ks) {
      short8 b = *(const short8*)&Wg_bf[(size_t)(jt * 16 + lrow) * 256 +
                                        (ks * 4 + lgrp) * 8];
      c = __builtin_amdgcn_mfma_f32_16x16x32_bf16(ar[ks], b, c, 0, 0, 0);
    }
    #pragma unroll
    for (int ks = 0; ks < 4; ++ks) {
      short8 b = *(const short8*)&Wg_bf[(size_t)(jt * 16 + lrow) * 256 +
                                        ((ks + 4) * 4 + lgrp) * 8];
      c = __builtin_amdgcn_mfma_f32_16x16x32_bf16(at[ks], b, c, 0, 0, 0);
    }
    int col = jt * 16 + lrow;
    #pragma unroll
    for (int r = 0; r < 4; ++r) {
      int rr = rbase + r;
      if (rr < n) {
        float g = 1.f / (1.f + __expf(-c[r]));
        float rowf = rowsT[(size_t)rr * DD + col];
        out[(size_t)rr * DD + col] = g * rowf + (1.f - g) * tac[jt][r];
      }
    }
  }
}

extern "C" void kernel_launch(void* const* d_in, const int* in_sizes, int n_in,
                              void* d_out, int out_size, void* d_ws, size_t ws_size,
                              hipStream_t stream) {
  const float* A      = (const float*)d_in[0];
  const float* B      = (const float*)d_in[1];
  const float* W_fwd  = (const float*)d_in[2];
  const float* b_fwd  = (const float*)d_in[3];
  const float* W_rev  = (const float*)d_in[4];
  const float* b_rev  = (const float*)d_in[5];
  const float* W_gate = (const float*)d_in[6];
  const float* b_gate = (const float*)d_in[7];
  const int*   src    = (const int*)d_in[8];
  const int*   dst    = (const int*)d_in[9];

  const int n_a = in_sizes[0] / DD;
  const int n_b = in_sizes[1] / DD;
  const int E   = in_sizes[8];
  const int n_total = n_a + n_b;

  float* out = (float*)d_out;

  // workspace layout
  int* cnt      = (int*)d_ws;                        // [n_total]
  int* start    = cnt + n_total;                     // [n_total]
  int* cursor   = start + n_total;                   // [n_total]
  int* partials = cursor + n_total;                  // [1024]
  int* partner  = partials + 1024;                   // [2E]
  uintptr_t wp = (uintptr_t)(partner + 2 * (size_t)E);
  wp = (wp + 63) & ~(uintptr_t)63;
  unsigned short* wbf = (unsigned short*)wp;         // [65536] bf16 weights
  unsigned short* rows_bf = wbf + 65536;             // [(n_a+n_b)*128] bf16 rows
  unsigned short* A_bf = rows_bf;
  unsigned short* B_bf = rows_bf + (size_t)n_a * DD;

  const int nch  = (n_total + SCHUNK - 1) / SCHUNK;
  const int eblk = (E + 255) / 256;
  const int nA4  = n_a * (DD / 4);
  const int nt4  = n_total * (DD / 4);

  hipMemsetAsync(cnt, 0, (size_t)n_total * sizeof(int), stream);

  rowconv_kernel<<<2048, 256, 0, stream>>>(A, B, rows_bf, nA4, nt4);
  wconv_kernel<<<256, 256, 0, stream>>>(W_rev, W_fwd, W_gate, wbf);

  hist_kernel<<<eblk, 256, 0, stream>>>(src, dst, cnt, n_a, E);
  scan1_kernel<<<nch, 256, 0, stream>>>(cnt, n_total, partials);
  scan2_kernel<<<1, 256, 0, stream>>>(partials, nch);
  scan3_kernel<<<nch, 256, 0, stream>>>(cnt, n_total, partials, start, cursor);
  scatter_ids_kernel<<<eblk, 256, 0, stream>>>(src, dst, cursor, partner, n_a, E);

  // A range: gathers B rows, t = mean @ W_rev^T + b_rev
  mega_kernel<<<(n_a + 63) / 64, 256, 0, stream>>>(
      A, B_bf, partner, start, cnt, wbf, wbf + 32768, b_rev, b_gate, out, n_a);
  // B range: gathers A rows, t = mean @ W_fwd^T + b_fwd
  mega_kernel<<<(n_b + 63) / 64, 256, 0, stream>>>(
      B, A_bf, partner, start + n_a, cnt + n_a, wbf + 16384, wbf + 32768,
      b_fwd, b_gate, out + (size_t)n_a * DD, n_b);
}

// Round 5
// 677.862 us; speedup vs baseline: 1.1459x; 1.1459x over previous
//
#include <hip/hip_runtime.h>
#include <math.h>

#define DD 128
#define SCHUNK 2048

typedef __attribute__((ext_vector_type(8))) short short8;
typedef __attribute__((ext_vector_type(4))) float f32x4;
typedef __attribute__((ext_vector_type(4))) unsigned short us4;

__device__ __forceinline__ unsigned short f2bf(float f) {
  unsigned int u = __builtin_bit_cast(unsigned int, f);
  u = (u + 0x7FFFu + ((u >> 16) & 1u)) >> 16;   // RNE (finite inputs)
  return (unsigned short)u;
}

__device__ __forceinline__ short8 pack8(float4 a, float4 b) {
  short8 r;
  r[0] = (short)f2bf(a.x); r[1] = (short)f2bf(a.y);
  r[2] = (short)f2bf(a.z); r[3] = (short)f2bf(a.w);
  r[4] = (short)f2bf(b.x); r[5] = (short)f2bf(b.y);
  r[6] = (short)f2bf(b.z); r[7] = (short)f2bf(b.w);
  return r;
}

// ---------------------------------------------------------------------------
// Row conversion f32 -> bf16: [A | B] into one table.
// ---------------------------------------------------------------------------
__global__ __launch_bounds__(256) void rowconv_kernel(
    const float* __restrict__ A, const float* __restrict__ B,
    unsigned short* __restrict__ dst, int nA4, int ntot4)
{
  int stride = gridDim.x * 256;
  for (int i = blockIdx.x * 256 + threadIdx.x; i < ntot4; i += stride) {
    float4 v = (i < nA4) ? ((const float4*)A)[i] : ((const float4*)B)[i - nA4];
    us4 o;
    o[0] = f2bf(v.x); o[1] = f2bf(v.y); o[2] = f2bf(v.z); o[3] = f2bf(v.w);
    ((us4*)dst)[i] = o;
  }
}

// ---------------------------------------------------------------------------
// Weight conversion f32 -> bf16: [Wrev | Wfwd | Wgate]
// ---------------------------------------------------------------------------
__global__ __launch_bounds__(256) void wconv_kernel(
    const float* __restrict__ Wrev, const float* __restrict__ Wfwd,
    const float* __restrict__ Wgate, unsigned short* __restrict__ dst)
{
  int i = blockIdx.x * 256 + threadIdx.x;   // 65536 total
  float v;
  if (i < 16384) v = Wrev[i];
  else if (i < 32768) v = Wfwd[i - 16384];
  else v = Wgate[i - 32768];
  dst[i] = f2bf(v);
}

// ---------------------------------------------------------------------------
// Phase 1: degree histogram
// ---------------------------------------------------------------------------
__global__ __launch_bounds__(256) void hist_kernel(
    const int* __restrict__ src, const int* __restrict__ dst,
    int* __restrict__ cnt, int n_a, int E)
{
  int e = blockIdx.x * 256 + threadIdx.x;
  if (e >= E) return;
  atomicAdd(&cnt[src[e]], 1);
  atomicAdd(&cnt[n_a + dst[e]], 1);
}

// ---------------------------------------------------------------------------
// Phase 2: exclusive scan (3 kernels)
// ---------------------------------------------------------------------------
__global__ __launch_bounds__(256) void scan1_kernel(
    const int* __restrict__ cnt, int n, int* __restrict__ partials)
{
  __shared__ int sd[256];
  int t = threadIdx.x;
  int base = blockIdx.x * SCHUNK;
  int s = 0;
  #pragma unroll
  for (int k = 0; k < 8; ++k) {
    int i = base + t * 8 + k;
    s += (i < n) ? cnt[i] : 0;
  }
  sd[t] = s;
  __syncthreads();
  for (int off = 128; off > 0; off >>= 1) {
    if (t < off) sd[t] += sd[t + off];
    __syncthreads();
  }
  if (t == 0) partials[blockIdx.x] = sd[0];
}

__global__ __launch_bounds__(256) void scan2_kernel(int* __restrict__ partials, int nch)
{
  __shared__ int buf[256];
  int t = threadIdx.x;
  int v = (t < nch) ? partials[t] : 0;
  buf[t] = v;
  __syncthreads();
  for (int off = 1; off < 256; off <<= 1) {
    int x = (t >= off) ? buf[t - off] : 0;
    __syncthreads();
    buf[t] += x;
    __syncthreads();
  }
  if (t < nch) partials[t] = buf[t] - v;   // exclusive
}

__global__ __launch_bounds__(256) void scan3_kernel(
    const int* __restrict__ cnt, int n, const int* __restrict__ partials,
    int* __restrict__ start, int* __restrict__ cursor)
{
  __shared__ int sd[256];
  int t = threadIdx.x;
  int base = blockIdx.x * SCHUNK;
  int loc[8];
  int s = 0;
  #pragma unroll
  for (int k = 0; k < 8; ++k) {
    int i = base + t * 8 + k;
    loc[k] = (i < n) ? cnt[i] : 0;
    s += loc[k];
  }
  sd[t] = s;
  __syncthreads();
  for (int off = 1; off < 256; off <<= 1) {
    int x = (t >= off) ? sd[t - off] : 0;
    __syncthreads();
    sd[t] += x;
    __syncthreads();
  }
  int off = partials[blockIdx.x] + sd[t] - s;
  #pragma unroll
  for (int k = 0; k < 8; ++k) {
    int i = base + t * 8 + k;
    if (i < n) { start[i] = off; cursor[i] = off; }
    off += loc[k];
  }
}

// ---------------------------------------------------------------------------
// Phase 3: scatter partner ids
// ---------------------------------------------------------------------------
__global__ __launch_bounds__(256) void scatter_ids_kernel(
    const int* __restrict__ src, const int* __restrict__ dst,
    int* __restrict__ cursor, int* __restrict__ partner, int n_a, int E)
{
  int e = blockIdx.x * 256 + threadIdx.x;
  if (e >= E) return;
  int s = src[e], d = dst[e];
  int p = atomicAdd(&cursor[s], 1);
  partner[p] = d;
  int q = atomicAdd(&cursor[n_a + d], 1);
  partner[q] = s;
}

// ---------------------------------------------------------------------------
// Phase 4: one wave per row, gather bf16 partner rows (L3-resident), mean ->
// bf16 mean table. Max occupancy; 8-deep load unroll for MLP.
// ---------------------------------------------------------------------------
__global__ __launch_bounds__(256) void aggregate_mean_bf16_kernel(
    const unsigned short* __restrict__ A_bf,
    const unsigned short* __restrict__ B_bf,
    const int* __restrict__ partner, const int* __restrict__ start,
    const int* __restrict__ cnt, unsigned short* __restrict__ mean_bf,
    int n_a, int n_total)
{
  int wid = (blockIdx.x * 256 + threadIdx.x) >> 6;
  if (wid >= n_total) return;
  int lane = threadIdx.x & 63;
  int s0 = start[wid], c = cnt[wid];
  const unsigned short* tbl = (wid < n_a) ? B_bf : A_bf;
  float ax = 0.f, ay = 0.f;
  int k = 0;
  for (; k + 8 <= c; k += 8) {
    unsigned v0 = *(const unsigned*)(tbl + (size_t)partner[s0 + k + 0] * DD + 2 * lane);
    unsigned v1 = *(const unsigned*)(tbl + (size_t)partner[s0 + k + 1] * DD + 2 * lane);
    unsigned v2 = *(const unsigned*)(tbl + (size_t)partner[s0 + k + 2] * DD + 2 * lane);
    unsigned v3 = *(const unsigned*)(tbl + (size_t)partner[s0 + k + 3] * DD + 2 * lane);
    unsigned v4 = *(const unsigned*)(tbl + (size_t)partner[s0 + k + 4] * DD + 2 * lane);
    unsigned v5 = *(const unsigned*)(tbl + (size_t)partner[s0 + k + 5] * DD + 2 * lane);
    unsigned v6 = *(const unsigned*)(tbl + (size_t)partner[s0 + k + 6] * DD + 2 * lane);
    unsigned v7 = *(const unsigned*)(tbl + (size_t)partner[s0 + k + 7] * DD + 2 * lane);
    ax += __builtin_bit_cast(float, v0 << 16); ay += __builtin_bit_cast(float, v0 & 0xFFFF0000u);
    ax += __builtin_bit_cast(float, v1 << 16); ay += __builtin_bit_cast(float, v1 & 0xFFFF0000u);
    ax += __builtin_bit_cast(float, v2 << 16); ay += __builtin_bit_cast(float, v2 & 0xFFFF0000u);
    ax += __builtin_bit_cast(float, v3 << 16); ay += __builtin_bit_cast(float, v3 & 0xFFFF0000u);
    ax += __builtin_bit_cast(float, v4 << 16); ay += __builtin_bit_cast(float, v4 & 0xFFFF0000u);
    ax += __builtin_bit_cast(float, v5 << 16); ay += __builtin_bit_cast(float, v5 & 0xFFFF0000u);
    ax += __builtin_bit_cast(float, v6 << 16); ay += __builtin_bit_cast(float, v6 & 0xFFFF0000u);
    ax += __builtin_bit_cast(float, v7 << 16); ay += __builtin_bit_cast(float, v7 & 0xFFFF0000u);
  }
  for (; k < c; ++k) {
    unsigned v = *(const unsigned*)(tbl + (size_t)partner[s0 + k] * DD + 2 * lane);
    ax += __builtin_bit_cast(float, v << 16);
    ay += __builtin_bit_cast(float, v & 0xFFFF0000u);
  }
  float inv = (c > 0) ? (1.f / (float)c) : 0.f;
  unsigned pk = (unsigned)f2bf(ax * inv) | ((unsigned)f2bf(ay * inv) << 16);
  *(unsigned*)&mean_bf[(size_t)wid * DD + 2 * lane] = pk;
}

// ---------------------------------------------------------------------------
// Phase 5+6 fused (MFMA), mean from GLOBAL bf16 (no staging, no barriers):
//   t = (cnt>0) ? mean @ Wr^T + br : 0
//   u = row @ Wg[:,:128]^T + t @ Wg[:,128:]^T + bg
//   out = sigmoid(u)*row + (1-sigmoid(u))*t
// 256 threads = 4 waves x 16 rows. Weights from global (L2-resident).
// Only LDS: 4 KB/wave patch for the t C/D->A relayout.
// ---------------------------------------------------------------------------
__global__ __launch_bounds__(256, 4) void fused_post_kernel(
    const float* __restrict__ rowsT,            // f32 rows of this range
    const unsigned short* __restrict__ mean_bf, // bf16 mean of this range
    const int* __restrict__ cnt,                // range-local
    const unsigned short* __restrict__ Wr_bf,   // [128][128] bf16
    const unsigned short* __restrict__ Wg_bf,   // [128][256] bf16
    const float* __restrict__ br, const float* __restrict__ bg,
    float* __restrict__ out, int n)
{
  __shared__ unsigned short patch[4][16 * DD];   // 16 KB

  const int t = threadIdx.x;
  const int wid  = t >> 6;
  const int lane = t & 63;
  const int lrow = lane & 15;
  const int lgrp = lane >> 4;
  const int m0 = blockIdx.x * 64 + wid * 16;
  if (m0 >= n) return;
  unsigned short* tw = patch[wid];

  const int mr = m0 + lrow;
  const bool rowok = mr < n;

  // A-fragments of mean: direct 16B global loads
  short8 am[4];
  #pragma unroll
  for (int ks = 0; ks < 4; ++ks) {
    short8 v = {0, 0, 0, 0, 0, 0, 0, 0};
    if (rowok)
      v = *(const short8*)&mean_bf[(size_t)mr * DD + ks * 32 + lgrp * 8];
    am[ks] = v;
  }

  // A-fragments of row (f32 -> bf16), issued early to overlap with t-GEMM
  short8 ar[4];
  #pragma unroll
  for (int ks = 0; ks < 4; ++ks) {
    int k0 = ks * 32 + lgrp * 8;
    float4 u0 = make_float4(0.f, 0.f, 0.f, 0.f), u1 = u0;
    if (rowok) {
      u0 = *(const float4*)(rowsT + (size_t)mr * DD + k0);
      u1 = *(const float4*)(rowsT + (size_t)mr * DD + k0 + 4);
    }
    ar[ks] = pack8(u0, u1);
  }

  // t = mean @ Wr^T + br
  f32x4 tac[8];
  #pragma unroll
  for (int jt = 0; jt < 8; ++jt) {
    float bv = br[jt * 16 + lrow];
    f32x4 c = {bv, bv, bv, bv};
    #pragma unroll
    for (int ks = 0; ks < 4; ++ks) {
      short8 b = *(const short8*)&Wr_bf[(size_t)(jt * 16 + lrow) * 128 +
                                        (ks * 4 + lgrp) * 8];
      c = __builtin_amdgcn_mfma_f32_16x16x32_bf16(am[ks], b, c, 0, 0, 0);
    }
    tac[jt] = c;
  }

  // cnt==0 -> t = 0 (reference: mean_msg exactly 0)
  const int rbase = m0 + lgrp * 4;
  #pragma unroll
  for (int r = 0; r < 4; ++r) {
    int rr = rbase + r;
    int cv = (rr < n) ? cnt[rr] : 0;
    if (cv == 0) {
      #pragma unroll
      for (int jt = 0; jt < 8; ++jt) tac[jt][r] = 0.f;
    }
  }

  // relayout t: C/D layout -> per-wave patch (bf16, octet-swizzled)
  #pragma unroll
  for (int jt = 0; jt < 8; ++jt) {
    int col = jt * 16 + lrow;
    int oc = col >> 3, ci = col & 7;
    #pragma unroll
    for (int r = 0; r < 4; ++r) {
      int rr4 = lgrp * 4 + r;
      tw[rr4 * DD + ((oc ^ rr4) << 3) + ci] = f2bf(tac[jt][r]);
    }
  }

  // A-fragments of t from patch (same-wave; compiler inserts lgkm wait)
  short8 at[4];
  #pragma unroll
  for (int ks = 0; ks < 4; ++ks) {
    int o = ks * 4 + lgrp;
    at[ks] = *(short8*)&tw[lrow * DD + ((o ^ lrow) << 3)];
  }

  // gate GEMM (K=256) + blend + store
  #pragma unroll
  for (int jt = 0; jt < 8; ++jt) {
    float bv = bg[jt * 16 + lrow];
    f32x4 c = {bv, bv, bv, bv};
    #pragma unroll
    for (int ks = 0; ks < 4; ++ks) {
      short8 b = *(const short8*)&Wg_bf[(size_t)(jt * 16 + lrow) * 256 +
                                        (ks * 4 + lgrp) * 8];
      c = __builtin_amdgcn_mfma_f32_16x16x32_bf16(ar[ks], b, c, 0, 0, 0);
    }
    #pragma unroll
    for (int ks = 0; ks < 4; ++ks) {
      short8 b = *(const short8*)&Wg_bf[(size_t)(jt * 16 + lrow) * 256 +
                                        ((ks + 4) * 4 + lgrp) * 8];
      c = __builtin_amdgcn_mfma_f32_16x16x32_bf16(at[ks], b, c, 0, 0, 0);
    }
    int col = jt * 16 + lrow;
    #pragma unroll
    for (int r = 0; r < 4; ++r) {
      int rr = rbase + r;
      if (rr < n) {
        float g = 1.f / (1.f + __expf(-c[r]));
        float rowf = rowsT[(size_t)rr * DD + col];
        out[(size_t)rr * DD + col] = g * rowf + (1.f - g) * tac[jt][r];
      }
    }
  }
}

extern "C" void kernel_launch(void* const* d_in, const int* in_sizes, int n_in,
                              void* d_out, int out_size, void* d_ws, size_t ws_size,
                              hipStream_t stream) {
  const float* A      = (const float*)d_in[0];
  const float* B      = (const float*)d_in[1];
  const float* W_fwd  = (const float*)d_in[2];
  const float* b_fwd  = (const float*)d_in[3];
  const float* W_rev  = (const float*)d_in[4];
  const float* b_rev  = (const float*)d_in[5];
  const float* W_gate = (const float*)d_in[6];
  const float* b_gate = (const float*)d_in[7];
  const int*   src    = (const int*)d_in[8];
  const int*   dst    = (const int*)d_in[9];

  const int n_a = in_sizes[0] / DD;
  const int n_b = in_sizes[1] / DD;
  const int E   = in_sizes[8];
  const int n_total = n_a + n_b;

  float* out = (float*)d_out;

  // workspace layout
  int* cnt      = (int*)d_ws;                        // [n_total]
  int* start    = cnt + n_total;                     // [n_total]
  int* cursor   = start + n_total;                   // [n_total]
  int* partials = cursor + n_total;                  // [1024]
  int* partner  = partials + 1024;                   // [2E]
  uintptr_t wp = (uintptr_t)(partner + 2 * (size_t)E);
  wp = (wp + 63) & ~(uintptr_t)63;
  unsigned short* wbf = (unsigned short*)wp;         // [65536] bf16 weights
  unsigned short* rows_bf = wbf + 65536;             // [n_total*128] bf16 rows
  unsigned short* A_bf = rows_bf;
  unsigned short* B_bf = rows_bf + (size_t)n_a * DD;
  unsigned short* mean_bf = rows_bf + (size_t)n_total * DD;  // [n_total*128]

  const int nch  = (n_total + SCHUNK - 1) / SCHUNK;
  const int eblk = (E + 255) / 256;
  const int nA4  = n_a * (DD / 4);
  const int nt4  = n_total * (DD / 4);

  hipMemsetAsync(cnt, 0, (size_t)n_total * sizeof(int), stream);

  rowconv_kernel<<<2048, 256, 0, stream>>>(A, B, rows_bf, nA4, nt4);
  wconv_kernel<<<256, 256, 0, stream>>>(W_rev, W_fwd, W_gate, wbf);

  hist_kernel<<<eblk, 256, 0, stream>>>(src, dst, cnt, n_a, E);
  scan1_kernel<<<nch, 256, 0, stream>>>(cnt, n_total, partials);
  scan2_kernel<<<1, 256, 0, stream>>>(partials, nch);
  scan3_kernel<<<nch, 256, 0, stream>>>(cnt, n_total, partials, start, cursor);
  scatter_ids_kernel<<<eblk, 256, 0, stream>>>(src, dst, cursor, partner, n_a, E);

  aggregate_mean_bf16_kernel<<<(n_total + 3) / 4, 256, 0, stream>>>(
      A_bf, B_bf, partner, start, cnt, mean_bf, n_a, n_total);

  // A range: t = mean_a @ W_rev^T + b_rev
  fused_post_kernel<<<(n_a + 63) / 64, 256, 0, stream>>>(
      A, mean_bf, cnt, wbf, wbf + 32768, b_rev, b_gate, out, n_a);
  // B range: t = mean_b @ W_fwd^T + b_fwd
  fused_post_kernel<<<(n_b + 63) / 64, 256, 0, stream>>>(
      B, mean_bf + (size_t)n_a * DD, cnt + n_a, wbf + 16384, wbf + 32768,
      b_fwd, b_gate, out + (size_t)n_a * DD, n_b);
}

// Round 9
// 587.304 us; speedup vs baseline: 1.3225x; 1.1542x over previous
//
#include <hip/hip_runtime.h>
#include <math.h>

#define DD 128
#define SCHUNK 2048

typedef __attribute__((ext_vector_type(8))) short short8;
typedef __attribute__((ext_vector_type(4))) float f32x4;
typedef __attribute__((ext_vector_type(4))) unsigned short us4;

__device__ __forceinline__ unsigned short f2bf(float f) {
  unsigned int u = __builtin_bit_cast(unsigned int, f);
  u = (u + 0x7FFFu + ((u >> 16) & 1u)) >> 16;   // RNE (finite inputs)
  return (unsigned short)u;
}

__device__ __forceinline__ short8 pack8(float4 a, float4 b) {
  short8 r;
  r[0] = (short)f2bf(a.x); r[1] = (short)f2bf(a.y);
  r[2] = (short)f2bf(a.z); r[3] = (short)f2bf(a.w);
  r[4] = (short)f2bf(b.x); r[5] = (short)f2bf(b.y);
  r[6] = (short)f2bf(b.z); r[7] = (short)f2bf(b.w);
  return r;
}

// ---------------------------------------------------------------------------
// Row conversion f32 -> bf16: [A | B] into one table.
// ---------------------------------------------------------------------------
__global__ __launch_bounds__(256) void rowconv_kernel(
    const float* __restrict__ A, const float* __restrict__ B,
    unsigned short* __restrict__ dst, int nA4, int ntot4)
{
  int stride = gridDim.x * 256;
  for (int i = blockIdx.x * 256 + threadIdx.x; i < ntot4; i += stride) {
    float4 v = (i < nA4) ? ((const float4*)A)[i] : ((const float4*)B)[i - nA4];
    us4 o;
    o[0] = f2bf(v.x); o[1] = f2bf(v.y); o[2] = f2bf(v.z); o[3] = f2bf(v.w);
    ((us4*)dst)[i] = o;
  }
}

// ---------------------------------------------------------------------------
// Weight conversion f32 -> bf16: [Wrev | Wfwd | Wgate]
// ---------------------------------------------------------------------------
__global__ __launch_bounds__(256) void wconv_kernel(
    const float* __restrict__ Wrev, const float* __restrict__ Wfwd,
    const float* __restrict__ Wgate, unsigned short* __restrict__ dst)
{
  int i = blockIdx.x * 256 + threadIdx.x;   // 65536 total
  float v;
  if (i < 16384) v = Wrev[i];
  else if (i < 32768) v = Wfwd[i - 16384];
  else v = Wgate[i - 32768];
  dst[i] = f2bf(v);
}

// ---------------------------------------------------------------------------
// Phase 1: degree histogram
// ---------------------------------------------------------------------------
__global__ __launch_bounds__(256) void hist_kernel(
    const int* __restrict__ src, const int* __restrict__ dst,
    int* __restrict__ cnt, int n_a, int E)
{
  int e = blockIdx.x * 256 + threadIdx.x;
  if (e >= E) return;
  atomicAdd(&cnt[src[e]], 1);
  atomicAdd(&cnt[n_a + dst[e]], 1);
}

// ---------------------------------------------------------------------------
// Phase 2: exclusive scan (3 kernels)
// ---------------------------------------------------------------------------
__global__ __launch_bounds__(256) void scan1_kernel(
    const int* __restrict__ cnt, int n, int* __restrict__ partials)
{
  __shared__ int sd[256];
  int t = threadIdx.x;
  int base = blockIdx.x * SCHUNK;
  int s = 0;
  #pragma unroll
  for (int k = 0; k < 8; ++k) {
    int i = base + t * 8 + k;
    s += (i < n) ? cnt[i] : 0;
  }
  sd[t] = s;
  __syncthreads();
  for (int off = 128; off > 0; off >>= 1) {
    if (t < off) sd[t] += sd[t + off];
    __syncthreads();
  }
  if (t == 0) partials[blockIdx.x] = sd[0];
}

__global__ __launch_bounds__(256) void scan2_kernel(int* __restrict__ partials, int nch)
{
  __shared__ int buf[256];
  int t = threadIdx.x;
  int v = (t < nch) ? partials[t] : 0;
  buf[t] = v;
  __syncthreads();
  for (int off = 1; off < 256; off <<= 1) {
    int x = (t >= off) ? buf[t - off] : 0;
    __syncthreads();
    buf[t] += x;
    __syncthreads();
  }
  if (t < nch) partials[t] = buf[t] - v;   // exclusive
}

__global__ __launch_bounds__(256) void scan3_kernel(
    const int* __restrict__ cnt, int n, const int* __restrict__ partials,
    int* __restrict__ start, int* __restrict__ cursor)
{
  __shared__ int sd[256];
  int t = threadIdx.x;
  int base = blockIdx.x * SCHUNK;
  int loc[8];
  int s = 0;
  #pragma unroll
  for (int k = 0; k < 8; ++k) {
    int i = base + t * 8 + k;
    loc[k] = (i < n) ? cnt[i] : 0;
    s += loc[k];
  }
  sd[t] = s;
  __syncthreads();
  for (int off = 1; off < 256; off <<= 1) {
    int x = (t >= off) ? sd[t - off] : 0;
    __syncthreads();
    sd[t] += x;
    __syncthreads();
  }
  int off = partials[blockIdx.x] + sd[t] - s;
  #pragma unroll
  for (int k = 0; k < 8; ++k) {
    int i = base + t * 8 + k;
    if (i < n) { start[i] = off; cursor[i] = off; }
    off += loc[k];
  }
}

// ---------------------------------------------------------------------------
// Phase 3: scatter partner ids
// ---------------------------------------------------------------------------
__global__ __launch_bounds__(256) void scatter_ids_kernel(
    const int* __restrict__ src, const int* __restrict__ dst,
    int* __restrict__ cursor, int* __restrict__ partner, int n_a, int E)
{
  int e = blockIdx.x * 256 + threadIdx.x;
  if (e >= E) return;
  int s = src[e], d = dst[e];
  int p = atomicAdd(&cursor[s], 1);
  partner[p] = d;
  int q = atomicAdd(&cursor[n_a + d], 1);
  partner[q] = s;
}

// ---------------------------------------------------------------------------
// Phase 4: one wave per row, gather bf16 partner rows (L3-resident), mean ->
// bf16 mean table. Max occupancy; 8-deep load unroll for MLP.
// ---------------------------------------------------------------------------
__global__ __launch_bounds__(256) void aggregate_mean_bf16_kernel(
    const unsigned short* __restrict__ A_bf,
    const unsigned short* __restrict__ B_bf,
    const int* __restrict__ partner, const int* __restrict__ start,
    const int* __restrict__ cnt, unsigned short* __restrict__ mean_bf,
    int n_a, int n_total)
{
  int wid = (blockIdx.x * 256 + threadIdx.x) >> 6;
  if (wid >= n_total) return;
  int lane = threadIdx.x & 63;
  int s0 = start[wid], c = cnt[wid];
  const unsigned short* tbl = (wid < n_a) ? B_bf : A_bf;
  float ax = 0.f, ay = 0.f;
  int k = 0;
  for (; k + 8 <= c; k += 8) {
    unsigned v0 = *(const unsigned*)(tbl + (size_t)partner[s0 + k + 0] * DD + 2 * lane);
    unsigned v1 = *(const unsigned*)(tbl + (size_t)partner[s0 + k + 1] * DD + 2 * lane);
    unsigned v2 = *(const unsigned*)(tbl + (size_t)partner[s0 + k + 2] * DD + 2 * lane);
    unsigned v3 = *(const unsigned*)(tbl + (size_t)partner[s0 + k + 3] * DD + 2 * lane);
    unsigned v4 = *(const unsigned*)(tbl + (size_t)partner[s0 + k + 4] * DD + 2 * lane);
    unsigned v5 = *(const unsigned*)(tbl + (size_t)partner[s0 + k + 5] * DD + 2 * lane);
    unsigned v6 = *(const unsigned*)(tbl + (size_t)partner[s0 + k + 6] * DD + 2 * lane);
    unsigned v7 = *(const unsigned*)(tbl + (size_t)partner[s0 + k + 7] * DD + 2 * lane);
    ax += __builtin_bit_cast(float, v0 << 16); ay += __builtin_bit_cast(float, v0 & 0xFFFF0000u);
    ax += __builtin_bit_cast(float, v1 << 16); ay += __builtin_bit_cast(float, v1 & 0xFFFF0000u);
    ax += __builtin_bit_cast(float, v2 << 16); ay += __builtin_bit_cast(float, v2 & 0xFFFF0000u);
    ax += __builtin_bit_cast(float, v3 << 16); ay += __builtin_bit_cast(float, v3 & 0xFFFF0000u);
    ax += __builtin_bit_cast(float, v4 << 16); ay += __builtin_bit_cast(float, v4 & 0xFFFF0000u);
    ax += __builtin_bit_cast(float, v5 << 16); ay += __builtin_bit_cast(float, v5 & 0xFFFF0000u);
    ax += __builtin_bit_cast(float, v6 << 16); ay += __builtin_bit_cast(float, v6 & 0xFFFF0000u);
    ax += __builtin_bit_cast(float, v7 << 16); ay += __builtin_bit_cast(float, v7 & 0xFFFF0000u);
  }
  for (; k < c; ++k) {
    unsigned v = *(const unsigned*)(tbl + (size_t)partner[s0 + k] * DD + 2 * lane);
    ax += __builtin_bit_cast(float, v << 16);
    ay += __builtin_bit_cast(float, v & 0xFFFF0000u);
  }
  float inv = (c > 0) ? (1.f / (float)c) : 0.f;
  unsigned pk = (unsigned)f2bf(ax * inv) | ((unsigned)f2bf(ay * inv) << 16);
  *(unsigned*)&mean_bf[(size_t)wid * DD + 2 * lane] = pk;
}

// ---------------------------------------------------------------------------
// Phase 5+6 fused (MFMA) — ROUND-3-PROVEN BODY (single 16-row tile per wave,
// Wr+Wg+biases staged in LDS with octet-XOR swizzle, write-once/read-once
// per-wave patch). Only change vs round 3: mean A-fragments read directly
// from global bf16 mean (round-5-proven load) instead of staged f32 mean.
//   t = (cnt>0) ? mean @ Wr^T + br : 0
//   u = row @ Wg[:,:128]^T + t @ Wg[:,128:]^T + bg
//   out = sigmoid(u)*row + (1-sigmoid(u))*t
// 512 threads = 8 waves x 16 rows = 128 rows/block. LDS ~129 KB.
// ---------------------------------------------------------------------------
__global__ __launch_bounds__(512) void fused_post_kernel(
    const float* __restrict__ rowsT,            // f32 rows of this range
    const unsigned short* __restrict__ mean_bf, // bf16 mean of this range
    const int* __restrict__ cnt,                // range-local
    const unsigned short* __restrict__ Wr_bf,   // [128][128] bf16
    const unsigned short* __restrict__ Wg_bf,   // [128][256] bf16
    const float* __restrict__ br, const float* __restrict__ bg,
    float* __restrict__ out, int n)
{
  __shared__ unsigned short Wr_l[128 * 128];   // 32 KB
  __shared__ unsigned short Wg_l[128 * 256];   // 64 KB
  __shared__ float br_l[128];
  __shared__ float bg_l[128];
  __shared__ unsigned short t_l[8][16 * DD];   // 32 KB, per-wave patches

  const int t = threadIdx.x;
  // stage Wr (2048 16B-octets), swizzle octet index by (row & 15)
  for (int oi = t; oi < 2048; oi += 512) {
    int j = oi >> 4, o = oi & 15;
    *(short8*)&Wr_l[j * 128 + ((o ^ (j & 15)) << 3)] =
        *(const short8*)&Wr_bf[oi << 3];
  }
  // stage Wg (4096 octets)
  for (int oi = t; oi < 4096; oi += 512) {
    int j = oi >> 5, o = oi & 31;
    *(short8*)&Wg_l[j * 256 + ((o ^ (j & 15)) << 3)] =
        *(const short8*)&Wg_bf[oi << 3];
  }
  if (t < 128) { br_l[t] = br[t]; bg_l[t] = bg[t]; }
  __syncthreads();

  const int wid  = t >> 6;
  const int lane = t & 63;
  const int lrow = lane & 15;   // A/B fragment: row/col index
  const int lgrp = lane >> 4;   // k-octet group
  const int m0 = blockIdx.x * 128 + wid * 16;
  if (m0 >= n) return;
  unsigned short* tw = t_l[wid];

  const int mr = m0 + lrow;
  const bool rowok = mr < n;

  // A-fragments of mean: direct 16B global bf16 loads (round-5-proven)
  short8 am[4];
  #pragma unroll
  for (int ks = 0; ks < 4; ++ks) {
    short8 v = {0, 0, 0, 0, 0, 0, 0, 0};
    if (rowok)
      v = *(const short8*)&mean_bf[(size_t)mr * DD + ks * 32 + lgrp * 8];
    am[ks] = v;
  }

  // t = mean @ Wr^T + br
  f32x4 tac[8];
  #pragma unroll
  for (int jt = 0; jt < 8; ++jt) {
    float bv = br_l[jt * 16 + lrow];
    f32x4 c = {bv, bv, bv, bv};
    #pragma unroll
    for (int ks = 0; ks < 4; ++ks) {
      int o = ks * 4 + lgrp;
      short8 b = *(short8*)&Wr_l[(jt * 16 + lrow) * 128 + ((o ^ lrow) << 3)];
      c = __builtin_amdgcn_mfma_f32_16x16x32_bf16(am[ks], b, c, 0, 0, 0);
    }
    tac[jt] = c;
  }

  // cnt==0 -> t = 0 (reference: mean_msg exactly 0)
  const int rbase = m0 + lgrp * 4;
  #pragma unroll
  for (int r = 0; r < 4; ++r) {
    int rr = rbase + r;
    int cv = (rr < n) ? cnt[rr] : 0;
    if (cv == 0) {
      #pragma unroll
      for (int jt = 0; jt < 8; ++jt) tac[jt][r] = 0.f;
    }
  }

  // relayout t: C/D layout -> per-wave LDS patch (bf16, octet-swizzled)
  #pragma unroll
  for (int jt = 0; jt < 8; ++jt) {
    int col = jt * 16 + lrow;
    int oc = col >> 3, ci = col & 7;
    #pragma unroll
    for (int r = 0; r < 4; ++r) {
      int rr4 = lgrp * 4 + r;
      tw[rr4 * DD + ((oc ^ rr4) << 3) + ci] = f2bf(tac[jt][r]);
    }
  }

  // A-fragments of row (f32 -> bf16)
  short8 ar[4];
  #pragma unroll
  for (int ks = 0; ks < 4; ++ks) {
    int k0 = ks * 32 + lgrp * 8;
    float4 u0 = make_float4(0.f, 0.f, 0.f, 0.f), u1 = u0;
    if (rowok) {
      u0 = *(const float4*)(rowsT + (size_t)mr * DD + k0);
      u1 = *(const float4*)(rowsT + (size_t)mr * DD + k0 + 4);
    }
    ar[ks] = pack8(u0, u1);
  }

  // A-fragments of t (from the per-wave patch; same-wave RAW)
  short8 at[4];
  #pragma unroll
  for (int ks = 0; ks < 4; ++ks) {
    int o = ks * 4 + lgrp;
    at[ks] = *(short8*)&tw[lrow * DD + ((o ^ lrow) << 3)];
  }

  // gate GEMM (K=256) + blend + store
  #pragma unroll
  for (int jt = 0; jt < 8; ++jt) {
    float bv = bg_l[jt * 16 + lrow];
    f32x4 c = {bv, bv, bv, bv};
    #pragma unroll
    for (int ks = 0; ks < 4; ++ks) {
      int o = ks * 4 + lgrp;
      short8 b = *(short8*)&Wg_l[(jt * 16 + lrow) * 256 + ((o ^ lrow) << 3)];
      c = __builtin_amdgcn_mfma_f32_16x16x32_bf16(ar[ks], b, c, 0, 0, 0);
    }
    #pragma unroll
    for (int ks = 0; ks < 4; ++ks) {
      int o = (ks + 4) * 4 + lgrp;
      short8 b = *(short8*)&Wg_l[(jt * 16 + lrow) * 256 + ((o ^ lrow) << 3)];
      c = __builtin_amdgcn_mfma_f32_16x16x32_bf16(at[ks], b, c, 0, 0, 0);
    }
    int col = jt * 16 + lrow;
    #pragma unroll
    for (int r = 0; r < 4; ++r) {
      int rr = rbase + r;
      if (rr < n) {
        float g = 1.f / (1.f + __expf(-c[r]));
        float rowf = rowsT[(size_t)rr * DD + col];
        out[(size_t)rr * DD + col] = g * rowf + (1.f - g) * tac[jt][r];
      }
    }
  }
}

extern "C" void kernel_launch(void* const* d_in, const int* in_sizes, int n_in,
                              void* d_out, int out_size, void* d_ws, size_t ws_size,
                              hipStream_t stream) {
  const float* A      = (const float*)d_in[0];
  const float* B      = (const float*)d_in[1];
  const float* W_fwd  = (const float*)d_in[2];
  const float* b_fwd  = (const float*)d_in[3];
  const float* W_rev  = (const float*)d_in[4];
  const float* b_rev  = (const float*)d_in[5];
  const float* W_gate = (const float*)d_in[6];
  const float* b_gate = (const float*)d_in[7];
  const int*   src    = (const int*)d_in[8];
  const int*   dst    = (const int*)d_in[9];

  const int n_a = in_sizes[0] / DD;
  const int n_b = in_sizes[1] / DD;
  const int E   = in_sizes[8];
  const int n_total = n_a + n_b;

  float* out = (float*)d_out;

  // workspace layout
  int* cnt      = (int*)d_ws;                        // [n_total]
  int* start    = cnt + n_total;                     // [n_total]
  int* cursor   = start + n_total;                   // [n_total]
  int* partials = cursor + n_total;                  // [1024]
  int* partner  = partials + 1024;                   // [2E]
  uintptr_t wp = (uintptr_t)(partner + 2 * (size_t)E);
  wp = (wp + 63) & ~(uintptr_t)63;
  unsigned short* wbf = (unsigned short*)wp;         // [65536] bf16 weights
  unsigned short* rows_bf = wbf + 65536;             // [n_total*128] bf16 rows
  unsigned short* A_bf = rows_bf;
  unsigned short* B_bf = rows_bf + (size_t)n_a * DD;
  unsigned short* mean_bf = rows_bf + (size_t)n_total * DD;  // [n_total*128]

  const int nch  = (n_total + SCHUNK - 1) / SCHUNK;
  const int eblk = (E + 255) / 256;
  const int nA4  = n_a * (DD / 4);
  const int nt4  = n_total * (DD / 4);

  hipMemsetAsync(cnt, 0, (size_t)n_total * sizeof(int), stream);

  rowconv_kernel<<<2048, 256, 0, stream>>>(A, B, rows_bf, nA4, nt4);
  wconv_kernel<<<256, 256, 0, stream>>>(W_rev, W_fwd, W_gate, wbf);

  hist_kernel<<<eblk, 256, 0, stream>>>(src, dst, cnt, n_a, E);
  scan1_kernel<<<nch, 256, 0, stream>>>(cnt, n_total, partials);
  scan2_kernel<<<1, 256, 0, stream>>>(partials, nch);
  scan3_kernel<<<nch, 256, 0, stream>>>(cnt, n_total, partials, start, cursor);
  scatter_ids_kernel<<<eblk, 256, 0, stream>>>(src, dst, cursor, partner, n_a, E);

  aggregate_mean_bf16_kernel<<<(n_total + 3) / 4, 256, 0, stream>>>(
      A_bf, B_bf, partner, start, cnt, mean_bf, n_a, n_total);

  // A range: t = mean_a @ W_rev^T + b_rev
  fused_post_kernel<<<(n_a + 127) / 128, 512, 0, stream>>>(
      A, mean_bf, cnt, wbf, wbf + 32768, b_rev, b_gate, out, n_a);
  // B range: t = mean_b @ W_fwd^T + b_fwd
  fused_post_kernel<<<(n_b + 127) / 128, 512, 0, stream>>>(
      B, mean_bf + (size_t)n_a * DD, cnt + n_a, wbf + 16384, wbf + 32768,
      b_fwd, b_gate, out + (size_t)n_a * DD, n_b);
}

// Round 10
// 548.102 us; speedup vs baseline: 1.4171x; 1.0715x over previous
//
#include <hip/hip_runtime.h>
#include <math.h>

#define DD 128
#define SCHUNK 2048

typedef __attribute__((ext_vector_type(8))) short short8;
typedef __attribute__((ext_vector_type(4))) float f32x4;
typedef __attribute__((ext_vector_type(4))) unsigned short us4;

__device__ __forceinline__ unsigned short f2bf(float f) {
  unsigned int u = __builtin_bit_cast(unsigned int, f);
  u = (u + 0x7FFFu + ((u >> 16) & 1u)) >> 16;   // RNE (finite inputs)
  return (unsigned short)u;
}

__device__ __forceinline__ float b2f(unsigned short u) {
  return __builtin_bit_cast(float, ((unsigned)u) << 16);
}

// ---------------------------------------------------------------------------
// Row conversion f32 -> bf16: [A | B] into one table.
// ---------------------------------------------------------------------------
__global__ __launch_bounds__(256) void rowconv_kernel(
    const float* __restrict__ A, const float* __restrict__ B,
    unsigned short* __restrict__ dst, int nA4, int ntot4)
{
  int stride = gridDim.x * 256;
  for (int i = blockIdx.x * 256 + threadIdx.x; i < ntot4; i += stride) {
    float4 v = (i < nA4) ? ((const float4*)A)[i] : ((const float4*)B)[i - nA4];
    us4 o;
    o[0] = f2bf(v.x); o[1] = f2bf(v.y); o[2] = f2bf(v.z); o[3] = f2bf(v.w);
    ((us4*)dst)[i] = o;
  }
}

// ---------------------------------------------------------------------------
// Weight conversion f32 -> bf16: [Wrev | Wfwd | Wgate]
// ---------------------------------------------------------------------------
__global__ __launch_bounds__(256) void wconv_kernel(
    const float* __restrict__ Wrev, const float* __restrict__ Wfwd,
    const float* __restrict__ Wgate, unsigned short* __restrict__ dst)
{
  int i = blockIdx.x * 256 + threadIdx.x;   // 65536 total
  float v;
  if (i < 16384) v = Wrev[i];
  else if (i < 32768) v = Wfwd[i - 16384];
  else v = Wgate[i - 32768];
  dst[i] = f2bf(v);
}

// ---------------------------------------------------------------------------
// Phase 1: degree histogram
// ---------------------------------------------------------------------------
__global__ __launch_bounds__(256) void hist_kernel(
    const int* __restrict__ src, const int* __restrict__ dst,
    int* __restrict__ cnt, int n_a, int E)
{
  int e = blockIdx.x * 256 + threadIdx.x;
  if (e >= E) return;
  atomicAdd(&cnt[src[e]], 1);
  atomicAdd(&cnt[n_a + dst[e]], 1);
}

// ---------------------------------------------------------------------------
// Phase 2: exclusive scan (3 kernels)
// ---------------------------------------------------------------------------
__global__ __launch_bounds__(256) void scan1_kernel(
    const int* __restrict__ cnt, int n, int* __restrict__ partials)
{
  __shared__ int sd[256];
  int t = threadIdx.x;
  int base = blockIdx.x * SCHUNK;
  int s = 0;
  #pragma unroll
  for (int k = 0; k < 8; ++k) {
    int i = base + t * 8 + k;
    s += (i < n) ? cnt[i] : 0;
  }
  sd[t] = s;
  __syncthreads();
  for (int off = 128; off > 0; off >>= 1) {
    if (t < off) sd[t] += sd[t + off];
    __syncthreads();
  }
  if (t == 0) partials[blockIdx.x] = sd[0];
}

__global__ __launch_bounds__(256) void scan2_kernel(int* __restrict__ partials, int nch)
{
  __shared__ int buf[256];
  int t = threadIdx.x;
  int v = (t < nch) ? partials[t] : 0;
  buf[t] = v;
  __syncthreads();
  for (int off = 1; off < 256; off <<= 1) {
    int x = (t >= off) ? buf[t - off] : 0;
    __syncthreads();
    buf[t] += x;
    __syncthreads();
  }
  if (t < nch) partials[t] = buf[t] - v;   // exclusive
}

__global__ __launch_bounds__(256) void scan3_kernel(
    const int* __restrict__ cnt, int n, const int* __restrict__ partials,
    int* __restrict__ start, int* __restrict__ cursor)
{
  __shared__ int sd[256];
  int t = threadIdx.x;
  int base = blockIdx.x * SCHUNK;
  int loc[8];
  int s = 0;
  #pragma unroll
  for (int k = 0; k < 8; ++k) {
    int i = base + t * 8 + k;
    loc[k] = (i < n) ? cnt[i] : 0;
    s += loc[k];
  }
  sd[t] = s;
  __syncthreads();
  for (int off = 1; off < 256; off <<= 1) {
    int x = (t >= off) ? sd[t - off] : 0;
    __syncthreads();
    sd[t] += x;
    __syncthreads();
  }
  int off = partials[blockIdx.x] + sd[t] - s;
  #pragma unroll
  for (int k = 0; k < 8; ++k) {
    int i = base + t * 8 + k;
    if (i < n) { start[i] = off; cursor[i] = off; }
    off += loc[k];
  }
}

// ---------------------------------------------------------------------------
// Phase 3: scatter partner ids
// ---------------------------------------------------------------------------
__global__ __launch_bounds__(256) void scatter_ids_kernel(
    const int* __restrict__ src, const int* __restrict__ dst,
    int* __restrict__ cursor, int* __restrict__ partner, int n_a, int E)
{
  int e = blockIdx.x * 256 + threadIdx.x;
  if (e >= E) return;
  int s = src[e], d = dst[e];
  int p = atomicAdd(&cursor[s], 1);
  partner[p] = d;
  int q = atomicAdd(&cursor[n_a + d], 1);
  partner[q] = s;
}

// ---------------------------------------------------------------------------
// Phase 4: one wave per row; 32 lanes x 8B cover one 256B bf16 row, the two
// half-waves process even/odd edges (2 gathered rows per load instruction).
// Combine halves with one shfl_xor(32) per accumulator; lanes<32 write mean.
// ---------------------------------------------------------------------------
__global__ __launch_bounds__(256) void aggregate_mean_bf16_kernel(
    const unsigned short* __restrict__ A_bf,
    const unsigned short* __restrict__ B_bf,
    const int* __restrict__ partner, const int* __restrict__ start,
    const int* __restrict__ cnt, unsigned short* __restrict__ mean_bf,
    int n_a, int n_total)
{
  int wid = (blockIdx.x * 256 + threadIdx.x) >> 6;
  if (wid >= n_total) return;
  int lane = threadIdx.x & 63;
  int c2 = lane & 31;        // column group: elements 4*c2 .. 4*c2+3
  int h  = lane >> 5;        // edge parity within a pair
  int s0 = start[wid], c = cnt[wid];
  const unsigned short* tbl = (wid < n_a) ? B_bf : A_bf;
  float a0 = 0.f, a1 = 0.f, a2 = 0.f, a3 = 0.f;
  int k = 0;
  for (; k + 8 <= c; k += 8) {          // 4 pairs = 8 edges in flight
    int p0 = partner[s0 + k + 0 + h];
    int p1 = partner[s0 + k + 2 + h];
    int p2 = partner[s0 + k + 4 + h];
    int p3 = partner[s0 + k + 6 + h];
    us4 v0 = *(const us4*)(tbl + (size_t)p0 * DD + 4 * c2);
    us4 v1 = *(const us4*)(tbl + (size_t)p1 * DD + 4 * c2);
    us4 v2 = *(const us4*)(tbl + (size_t)p2 * DD + 4 * c2);
    us4 v3 = *(const us4*)(tbl + (size_t)p3 * DD + 4 * c2);
    a0 += b2f(v0[0]) + b2f(v1[0]) + b2f(v2[0]) + b2f(v3[0]);
    a1 += b2f(v0[1]) + b2f(v1[1]) + b2f(v2[1]) + b2f(v3[1]);
    a2 += b2f(v0[2]) + b2f(v1[2]) + b2f(v2[2]) + b2f(v3[2]);
    a3 += b2f(v0[3]) + b2f(v1[3]) + b2f(v2[3]) + b2f(v3[3]);
  }
  for (; k < c; k += 2) {               // tail pairs (possibly odd)
    int i = k + h;
    if (i < c) {
      int p = partner[s0 + i];
      us4 v = *(const us4*)(tbl + (size_t)p * DD + 4 * c2);
      a0 += b2f(v[0]); a1 += b2f(v[1]); a2 += b2f(v[2]); a3 += b2f(v[3]);
    }
  }
  a0 += __shfl_xor(a0, 32);
  a1 += __shfl_xor(a1, 32);
  a2 += __shfl_xor(a2, 32);
  a3 += __shfl_xor(a3, 32);
  if (lane < 32) {
    float inv = (c > 0) ? (1.f / (float)c) : 0.f;
    us4 o;
    o[0] = f2bf(a0 * inv); o[1] = f2bf(a1 * inv);
    o[2] = f2bf(a2 * inv); o[3] = f2bf(a3 * inv);
    *(us4*)&mean_bf[(size_t)wid * DD + 4 * c2] = o;
  }
}

// ---------------------------------------------------------------------------
// Phase 5+6 fused (MFMA) — round-9-proven body; only change: row fragments
// AND blend row come from the bf16 row table (no f32 rows, no pack8).
//   t = (cnt>0) ? mean @ Wr^T + br : 0
//   u = row @ Wg[:,:128]^T + t @ Wg[:,128:]^T + bg
//   out = sigmoid(u)*row + (1-sigmoid(u))*t
// 512 threads = 8 waves x 16 rows = 128 rows/block. LDS ~129 KB.
// ---------------------------------------------------------------------------
__global__ __launch_bounds__(512) void fused_post_kernel(
    const unsigned short* __restrict__ rows16,  // bf16 rows of this range
    const unsigned short* __restrict__ mean_bf, // bf16 mean of this range
    const int* __restrict__ cnt,                // range-local
    const unsigned short* __restrict__ Wr_bf,   // [128][128] bf16
    const unsigned short* __restrict__ Wg_bf,   // [128][256] bf16
    const float* __restrict__ br, const float* __restrict__ bg,
    float* __restrict__ out, int n)
{
  __shared__ unsigned short Wr_l[128 * 128];   // 32 KB
  __shared__ unsigned short Wg_l[128 * 256];   // 64 KB
  __shared__ float br_l[128];
  __shared__ float bg_l[128];
  __shared__ unsigned short t_l[8][16 * DD];   // 32 KB, per-wave patches

  const int t = threadIdx.x;
  // stage Wr (2048 16B-octets), swizzle octet index by (row & 15)
  for (int oi = t; oi < 2048; oi += 512) {
    int j = oi >> 4, o = oi & 15;
    *(short8*)&Wr_l[j * 128 + ((o ^ (j & 15)) << 3)] =
        *(const short8*)&Wr_bf[oi << 3];
  }
  // stage Wg (4096 octets)
  for (int oi = t; oi < 4096; oi += 512) {
    int j = oi >> 5, o = oi & 31;
    *(short8*)&Wg_l[j * 256 + ((o ^ (j & 15)) << 3)] =
        *(const short8*)&Wg_bf[oi << 3];
  }
  if (t < 128) { br_l[t] = br[t]; bg_l[t] = bg[t]; }
  __syncthreads();

  const int wid  = t >> 6;
  const int lane = t & 63;
  const int lrow = lane & 15;   // A/B fragment: row/col index
  const int lgrp = lane >> 4;   // k-octet group
  const int m0 = blockIdx.x * 128 + wid * 16;
  if (m0 >= n) return;
  unsigned short* tw = t_l[wid];

  const int mr = m0 + lrow;
  const bool rowok = mr < n;

  // A-fragments of mean: direct 16B global bf16 loads
  short8 am[4];
  #pragma unroll
  for (int ks = 0; ks < 4; ++ks) {
    short8 v = {0, 0, 0, 0, 0, 0, 0, 0};
    if (rowok)
      v = *(const short8*)&mean_bf[(size_t)mr * DD + ks * 32 + lgrp * 8];
    am[ks] = v;
  }

  // t = mean @ Wr^T + br
  f32x4 tac[8];
  #pragma unroll
  for (int jt = 0; jt < 8; ++jt) {
    float bv = br_l[jt * 16 + lrow];
    f32x4 c = {bv, bv, bv, bv};
    #pragma unroll
    for (int ks = 0; ks < 4; ++ks) {
      int o = ks * 4 + lgrp;
      short8 b = *(short8*)&Wr_l[(jt * 16 + lrow) * 128 + ((o ^ lrow) << 3)];
      c = __builtin_amdgcn_mfma_f32_16x16x32_bf16(am[ks], b, c, 0, 0, 0);
    }
    tac[jt] = c;
  }

  // cnt==0 -> t = 0 (reference: mean_msg exactly 0)
  const int rbase = m0 + lgrp * 4;
  #pragma unroll
  for (int r = 0; r < 4; ++r) {
    int rr = rbase + r;
    int cv = (rr < n) ? cnt[rr] : 0;
    if (cv == 0) {
      #pragma unroll
      for (int jt = 0; jt < 8; ++jt) tac[jt][r] = 0.f;
    }
  }

  // relayout t: C/D layout -> per-wave LDS patch (bf16, octet-swizzled)
  #pragma unroll
  for (int jt = 0; jt < 8; ++jt) {
    int col = jt * 16 + lrow;
    int oc = col >> 3, ci = col & 7;
    #pragma unroll
    for (int r = 0; r < 4; ++r) {
      int rr4 = lgrp * 4 + r;
      tw[rr4 * DD + ((oc ^ rr4) << 3) + ci] = f2bf(tac[jt][r]);
    }
  }

  // A-fragments of row: direct 16B global bf16 loads
  short8 ar[4];
  #pragma unroll
  for (int ks = 0; ks < 4; ++ks) {
    short8 v = {0, 0, 0, 0, 0, 0, 0, 0};
    if (rowok)
      v = *(const short8*)&rows16[(size_t)mr * DD + ks * 32 + lgrp * 8];
    ar[ks] = v;
  }

  // A-fragments of t (from the per-wave patch; same-wave RAW)
  short8 at[4];
  #pragma unroll
  for (int ks = 0; ks < 4; ++ks) {
    int o = ks * 4 + lgrp;
    at[ks] = *(short8*)&tw[lrow * DD + ((o ^ lrow) << 3)];
  }

  // gate GEMM (K=256) + blend + store
  #pragma unroll
  for (int jt = 0; jt < 8; ++jt) {
    float bv = bg_l[jt * 16 + lrow];
    f32x4 c = {bv, bv, bv, bv};
    #pragma unroll
    for (int ks = 0; ks < 4; ++ks) {
      int o = ks * 4 + lgrp;
      short8 b = *(short8*)&Wg_l[(jt * 16 + lrow) * 256 + ((o ^ lrow) << 3)];
      c = __builtin_amdgcn_mfma_f32_16x16x32_bf16(ar[ks], b, c, 0, 0, 0);
    }
    #pragma unroll
    for (int ks = 0; ks < 4; ++ks) {
      int o = (ks + 4) * 4 + lgrp;
      short8 b = *(short8*)&Wg_l[(jt * 16 + lrow) * 256 + ((o ^ lrow) << 3)];
      c = __builtin_amdgcn_mfma_f32_16x16x32_bf16(at[ks], b, c, 0, 0, 0);
    }
    int col = jt * 16 + lrow;
    #pragma unroll
    for (int r = 0; r < 4; ++r) {
      int rr = rbase + r;
      if (rr < n) {
        float g = 1.f / (1.f + __expf(-c[r]));
        float rowf = b2f(rows16[(size_t)rr * DD + col]);
        out[(size_t)rr * DD + col] = g * rowf + (1.f - g) * tac[jt][r];
      }
    }
  }
}

extern "C" void kernel_launch(void* const* d_in, const int* in_sizes, int n_in,
                              void* d_out, int out_size, void* d_ws, size_t ws_size,
                              hipStream_t stream) {
  const float* A      = (const float*)d_in[0];
  const float* B      = (const float*)d_in[1];
  const float* W_fwd  = (const float*)d_in[2];
  const float* b_fwd  = (const float*)d_in[3];
  const float* W_rev  = (const float*)d_in[4];
  const float* b_rev  = (const float*)d_in[5];
  const float* W_gate = (const float*)d_in[6];
  const float* b_gate = (const float*)d_in[7];
  const int*   src    = (const int*)d_in[8];
  const int*   dst    = (const int*)d_in[9];

  const int n_a = in_sizes[0] / DD;
  const int n_b = in_sizes[1] / DD;
  const int E   = in_sizes[8];
  const int n_total = n_a + n_b;

  float* out = (float*)d_out;

  // workspace layout
  int* cnt      = (int*)d_ws;                        // [n_total]
  int* start    = cnt + n_total;                     // [n_total]
  int* cursor   = start + n_total;                   // [n_total]
  int* partials = cursor + n_total;                  // [1024]
  int* partner  = partials + 1024;                   // [2E]
  uintptr_t wp = (uintptr_t)(partner + 2 * (size_t)E);
  wp = (wp + 63) & ~(uintptr_t)63;
  unsigned short* wbf = (unsigned short*)wp;         // [65536] bf16 weights
  unsigned short* rows_bf = wbf + 65536;             // [n_total*128] bf16 rows
  unsigned short* A_bf = rows_bf;
  unsigned short* B_bf = rows_bf + (size_t)n_a * DD;
  unsigned short* mean_bf = rows_bf + (size_t)n_total * DD;  // [n_total*128]

  const int nch  = (n_total + SCHUNK - 1) / SCHUNK;
  const int eblk = (E + 255) / 256;
  const int nA4  = n_a * (DD / 4);
  const int nt4  = n_total * (DD / 4);

  hipMemsetAsync(cnt, 0, (size_t)n_total * sizeof(int), stream);

  rowconv_kernel<<<2048, 256, 0, stream>>>(A, B, rows_bf, nA4, nt4);
  wconv_kernel<<<256, 256, 0, stream>>>(W_rev, W_fwd, W_gate, wbf);

  hist_kernel<<<eblk, 256, 0, stream>>>(src, dst, cnt, n_a, E);
  scan1_kernel<<<nch, 256, 0, stream>>>(cnt, n_total, partials);
  scan2_kernel<<<1, 256, 0, stream>>>(partials, nch);
  scan3_kernel<<<nch, 256, 0, stream>>>(cnt, n_total, partials, start, cursor);
  scatter_ids_kernel<<<eblk, 256, 0, stream>>>(src, dst, cursor, partner, n_a, E);

  aggregate_mean_bf16_kernel<<<(n_total + 3) / 4, 256, 0, stream>>>(
      A_bf, B_bf, partner, start, cnt, mean_bf, n_a, n_total);

  // A range: t = mean_a @ W_rev^T + b_rev
  fused_post_kernel<<<(n_a + 127) / 128, 512, 0, stream>>>(
      A_bf, mean_bf, cnt, wbf, wbf + 32768, b_rev, b_gate, out, n_a);
  // B range: t = mean_b @ W_fwd^T + b_fwd
  fused_post_kernel<<<(n_b + 127) / 128, 512, 0, stream>>>(
      B_bf, mean_bf + (size_t)n_a * DD, cnt + n_a, wbf + 16384, wbf + 32768,
      b_fwd, b_gate, out + (size_t)n_a * DD, n_b);
}

// Round 11
// 474.884 us; speedup vs baseline: 1.6356x; 1.1542x over previous
//
#include <hip/hip_runtime.h>
#include <math.h>

#define DD 128
#define SCHUNK 2048

typedef __attribute__((ext_vector_type(8))) short short8;
typedef __attribute__((ext_vector_type(4))) float f32x4;
typedef __attribute__((ext_vector_type(4))) unsigned short us4;

__device__ __forceinline__ unsigned short f2bf(float f) {
  unsigned int u = __builtin_bit_cast(unsigned int, f);
  u = (u + 0x7FFFu + ((u >> 16) & 1u)) >> 16;   // RNE (finite inputs)
  return (unsigned short)u;
}

__device__ __forceinline__ float b2f(unsigned short u) {
  return __builtin_bit_cast(float, ((unsigned)u) << 16);
}

// ---------------------------------------------------------------------------
// Row conversion f32 -> bf16: [A | B] into one table.
// ---------------------------------------------------------------------------
__global__ __launch_bounds__(256) void rowconv_kernel(
    const float* __restrict__ A, const float* __restrict__ B,
    unsigned short* __restrict__ dst, int nA4, int ntot4)
{
  int stride = gridDim.x * 256;
  for (int i = blockIdx.x * 256 + threadIdx.x; i < ntot4; i += stride) {
    float4 v = (i < nA4) ? ((const float4*)A)[i] : ((const float4*)B)[i - nA4];
    us4 o;
    o[0] = f2bf(v.x); o[1] = f2bf(v.y); o[2] = f2bf(v.z); o[3] = f2bf(v.w);
    ((us4*)dst)[i] = o;
  }
}

// ---------------------------------------------------------------------------
// Weight conversion f32 -> bf16: [Wrev | Wfwd | Wgate]
// ---------------------------------------------------------------------------
__global__ __launch_bounds__(256) void wconv_kernel(
    const float* __restrict__ Wrev, const float* __restrict__ Wfwd,
    const float* __restrict__ Wgate, unsigned short* __restrict__ dst)
{
  int i = blockIdx.x * 256 + threadIdx.x;   // 65536 total
  float v;
  if (i < 16384) v = Wrev[i];
  else if (i < 32768) v = Wfwd[i - 16384];
  else v = Wgate[i - 32768];
  dst[i] = f2bf(v);
}

// ---------------------------------------------------------------------------
// Phase 1: degree histogram (per-row counts)
// ---------------------------------------------------------------------------
__global__ __launch_bounds__(256) void hist_kernel(
    const int* __restrict__ src, const int* __restrict__ dst,
    int* __restrict__ cnt, int n_a, int E)
{
  int e = blockIdx.x * 256 + threadIdx.x;
  if (e >= E) return;
  atomicAdd(&cnt[src[e]], 1);
  atomicAdd(&cnt[n_a + dst[e]], 1);
}

// ---------------------------------------------------------------------------
// Phase 2: exclusive scan over row counts (3 kernels)
// ---------------------------------------------------------------------------
__global__ __launch_bounds__(256) void scan1_kernel(
    const int* __restrict__ cnt, int n, int* __restrict__ partials)
{
  __shared__ int sd[256];
  int t = threadIdx.x;
  int base = blockIdx.x * SCHUNK;
  int s = 0;
  #pragma unroll
  for (int k = 0; k < 8; ++k) {
    int i = base + t * 8 + k;
    s += (i < n) ? cnt[i] : 0;
  }
  sd[t] = s;
  __syncthreads();
  for (int off = 128; off > 0; off >>= 1) {
    if (t < off) sd[t] += sd[t + off];
    __syncthreads();
  }
  if (t == 0) partials[blockIdx.x] = sd[0];
}

__global__ __launch_bounds__(256) void scan2_kernel(int* __restrict__ partials, int nch)
{
  __shared__ int buf[256];
  int t = threadIdx.x;
  int v = (t < nch) ? partials[t] : 0;
  buf[t] = v;
  __syncthreads();
  for (int off = 1; off < 256; off <<= 1) {
    int x = (t >= off) ? buf[t - off] : 0;
    __syncthreads();
    buf[t] += x;
    __syncthreads();
  }
  if (t < nch) partials[t] = buf[t] - v;   // exclusive
}

__global__ __launch_bounds__(256) void scan3_kernel(
    const int* __restrict__ cnt, int n, const int* __restrict__ partials,
    int* __restrict__ start, int* __restrict__ cursor)
{
  __shared__ int sd[256];
  int t = threadIdx.x;
  int base = blockIdx.x * SCHUNK;
  int loc[8];
  int s = 0;
  #pragma unroll
  for (int k = 0; k < 8; ++k) {
    int i = base + t * 8 + k;
    loc[k] = (i < n) ? cnt[i] : 0;
    s += loc[k];
  }
  sd[t] = s;
  __syncthreads();
  for (int off = 1; off < 256; off <<= 1) {
    int x = (t >= off) ? sd[t - off] : 0;
    __syncthreads();
    sd[t] += x;
    __syncthreads();
  }
  int off = partials[blockIdx.x] + sd[t] - s;
  #pragma unroll
  for (int k = 0; k < 8; ++k) {
    int i = base + t * 8 + k;
    if (i < n) { start[i] = off; cursor[i] = off; }
    off += loc[k];
  }
}

// ---------------------------------------------------------------------------
// Phase 3a: bin histogram. Bins are position-balanced: A rows (deg~5) use
// 1024-row bins, B rows (deg~20) use 256-row bins -> ~5120 records/bin.
// ---------------------------------------------------------------------------
__global__ __launch_bounds__(256) void binhist_kernel(
    const int* __restrict__ src, const int* __restrict__ dst,
    int* __restrict__ binraw, int na_bins, int nbins, int E)
{
  __shared__ int h[1024];
  int t = threadIdx.x;
  for (int i = t; i < 1024; i += 256) h[i] = 0;
  __syncthreads();
  int stride = gridDim.x * 256;
  for (int e = blockIdx.x * 256 + t; e < E; e += stride) {
    int s = src[e], d = dst[e];
    atomicAdd(&h[s >> 10], 1);
    atomicAdd(&h[na_bins + (d >> 8)], 1);
  }
  __syncthreads();
  for (int i = t; i < nbins; i += 256)
    if (h[i]) atomicAdd(&binraw[i], h[i]);
}

// ---------------------------------------------------------------------------
// Phase 3b: exclusive scan over bin counts (single block, nbins <= 512)
// ---------------------------------------------------------------------------
__global__ __launch_bounds__(512) void binscan_kernel(
    const int* __restrict__ binraw, int nbins,
    int* __restrict__ binstart, int* __restrict__ bincur)
{
  __shared__ int buf[512];
  int t = threadIdx.x;
  int v = (t < nbins) ? binraw[t] : 0;
  buf[t] = v;
  __syncthreads();
  for (int off = 1; off < 512; off <<= 1) {
    int x = (t >= off) ? buf[t - off] : 0;
    __syncthreads();
    buf[t] += x;
    __syncthreads();
  }
  if (t < nbins) {
    int excl = buf[t] - v;
    binstart[t] = excl;
    bincur[t] = excl;
  }
}

// ---------------------------------------------------------------------------
// Phase 3c: binfill. Each block takes 4096 edges (8192 records), ranks them
// per-bin in LDS, reserves one dense run per bin per block in the global bin
// list, writes records (key=row, val=partner) as per-CU dense runs.
// ---------------------------------------------------------------------------
__global__ __launch_bounds__(512) void binfill_kernel(
    const int* __restrict__ src, const int* __restrict__ dst,
    int* __restrict__ bincur, uint2* __restrict__ binrec,
    int n_a, int na_bins, int nbins, int E)
{
  __shared__ int lcnt[1024];
  __shared__ int goff[1024];
  const int t = threadIdx.x;
  const int base = blockIdx.x * 4096;
  for (int i = t; i < 1024; i += 512) lcnt[i] = 0;
  __syncthreads();

  int bins[16], ranks[16];
  unsigned keys[16], vals[16];
  #pragma unroll
  for (int j = 0; j < 8; ++j) {
    int e = base + j * 512 + t;
    int i0 = 2 * j, i1 = 2 * j + 1;
    if (e < E) {
      int s = src[e], d = dst[e];
      bins[i0] = s >> 10;               keys[i0] = (unsigned)s;       vals[i0] = (unsigned)d;
      bins[i1] = na_bins + (d >> 8);    keys[i1] = (unsigned)(n_a + d); vals[i1] = (unsigned)s;
      ranks[i0] = atomicAdd(&lcnt[bins[i0]], 1);
      ranks[i1] = atomicAdd(&lcnt[bins[i1]], 1);
    } else {
      bins[i0] = -1; bins[i1] = -1;
      ranks[i0] = 0;  ranks[i1] = 0;
      keys[i0] = 0;   keys[i1] = 0;
      vals[i0] = 0;   vals[i1] = 0;
    }
  }
  __syncthreads();
  for (int b = t; b < nbins; b += 512)
    if (lcnt[b]) goff[b] = atomicAdd(&bincur[b], lcnt[b]);
  __syncthreads();
  #pragma unroll
  for (int i = 0; i < 16; ++i) {
    if (bins[i] >= 0) {
      int p = goff[bins[i]] + ranks[i];
      binrec[p] = make_uint2(keys[i], vals[i]);
    }
  }
}

// ---------------------------------------------------------------------------
// Phase 3d: fine scatter, one block per bin. The bin's cursor (<=4KB) and
// partner region (~20KB) are exclusively owned -> L2-local, footprint-bound
// writebacks instead of per-access line thrash.
// ---------------------------------------------------------------------------
__global__ __launch_bounds__(256) void binscatter_kernel(
    const uint2* __restrict__ binrec, const int* __restrict__ binstart,
    const int* __restrict__ binend, int* __restrict__ cursor,
    int* __restrict__ partner)
{
  int b = blockIdx.x;
  int s0 = binstart[b], e0 = binend[b];
  for (int i = s0 + threadIdx.x; i < e0; i += 256) {
    uint2 r = binrec[i];
    int pos = atomicAdd(&cursor[r.x], 1);
    partner[pos] = (int)r.y;
  }
}

// ---------------------------------------------------------------------------
// Phase 4: one wave per row; 32 lanes x 8B cover one 256B bf16 row, the two
// half-waves process even/odd edges. Combine with one shfl_xor(32) per acc.
// ---------------------------------------------------------------------------
__global__ __launch_bounds__(256) void aggregate_mean_bf16_kernel(
    const unsigned short* __restrict__ A_bf,
    const unsigned short* __restrict__ B_bf,
    const int* __restrict__ partner, const int* __restrict__ start,
    const int* __restrict__ cnt, unsigned short* __restrict__ mean_bf,
    int n_a, int n_total)
{
  int wid = (blockIdx.x * 256 + threadIdx.x) >> 6;
  if (wid >= n_total) return;
  int lane = threadIdx.x & 63;
  int c2 = lane & 31;        // column group: elements 4*c2 .. 4*c2+3
  int h  = lane >> 5;        // edge parity within a pair
  int s0 = start[wid], c = cnt[wid];
  const unsigned short* tbl = (wid < n_a) ? B_bf : A_bf;
  float a0 = 0.f, a1 = 0.f, a2 = 0.f, a3 = 0.f;
  int k = 0;
  for (; k + 8 <= c; k += 8) {          // 4 pairs = 8 edges in flight
    int p0 = partner[s0 + k + 0 + h];
    int p1 = partner[s0 + k + 2 + h];
    int p2 = partner[s0 + k + 4 + h];
    int p3 = partner[s0 + k + 6 + h];
    us4 v0 = *(const us4*)(tbl + (size_t)p0 * DD + 4 * c2);
    us4 v1 = *(const us4*)(tbl + (size_t)p1 * DD + 4 * c2);
    us4 v2 = *(const us4*)(tbl + (size_t)p2 * DD + 4 * c2);
    us4 v3 = *(const us4*)(tbl + (size_t)p3 * DD + 4 * c2);
    a0 += b2f(v0[0]) + b2f(v1[0]) + b2f(v2[0]) + b2f(v3[0]);
    a1 += b2f(v0[1]) + b2f(v1[1]) + b2f(v2[1]) + b2f(v3[1]);
    a2 += b2f(v0[2]) + b2f(v1[2]) + b2f(v2[2]) + b2f(v3[2]);
    a3 += b2f(v0[3]) + b2f(v1[3]) + b2f(v2[3]) + b2f(v3[3]);
  }
  for (; k < c; k += 2) {               // tail pairs (possibly odd)
    int i = k + h;
    if (i < c) {
      int p = partner[s0 + i];
      us4 v = *(const us4*)(tbl + (size_t)p * DD + 4 * c2);
      a0 += b2f(v[0]); a1 += b2f(v[1]); a2 += b2f(v[2]); a3 += b2f(v[3]);
    }
  }
  a0 += __shfl_xor(a0, 32);
  a1 += __shfl_xor(a1, 32);
  a2 += __shfl_xor(a2, 32);
  a3 += __shfl_xor(a3, 32);
  if (lane < 32) {
    float inv = (c > 0) ? (1.f / (float)c) : 0.f;
    us4 o;
    o[0] = f2bf(a0 * inv); o[1] = f2bf(a1 * inv);
    o[2] = f2bf(a2 * inv); o[3] = f2bf(a3 * inv);
    *(us4*)&mean_bf[(size_t)wid * DD + 4 * c2] = o;
  }
}

// ---------------------------------------------------------------------------
// Phase 5+6 fused (MFMA) — round-9/10-proven body (single 16-row tile/wave).
//   t = (cnt>0) ? mean @ Wr^T + br : 0
//   u = row @ Wg[:,:128]^T + t @ Wg[:,128:]^T + bg
//   out = sigmoid(u)*row + (1-sigmoid(u))*t
// ---------------------------------------------------------------------------
__global__ __launch_bounds__(512) void fused_post_kernel(
    const unsigned short* __restrict__ rows16,  // bf16 rows of this range
    const unsigned short* __restrict__ mean_bf, // bf16 mean of this range
    const int* __restrict__ cnt,                // range-local
    const unsigned short* __restrict__ Wr_bf,   // [128][128] bf16
    const unsigned short* __restrict__ Wg_bf,   // [128][256] bf16
    const float* __restrict__ br, const float* __restrict__ bg,
    float* __restrict__ out, int n)
{
  __shared__ unsigned short Wr_l[128 * 128];   // 32 KB
  __shared__ unsigned short Wg_l[128 * 256];   // 64 KB
  __shared__ float br_l[128];
  __shared__ float bg_l[128];
  __shared__ unsigned short t_l[8][16 * DD];   // 32 KB, per-wave patches

  const int t = threadIdx.x;
  // stage Wr (2048 16B-octets), swizzle octet index by (row & 15)
  for (int oi = t; oi < 2048; oi += 512) {
    int j = oi >> 4, o = oi & 15;
    *(short8*)&Wr_l[j * 128 + ((o ^ (j & 15)) << 3)] =
        *(const short8*)&Wr_bf[oi << 3];
  }
  // stage Wg (4096 octets)
  for (int oi = t; oi < 4096; oi += 512) {
    int j = oi >> 5, o = oi & 31;
    *(short8*)&Wg_l[j * 256 + ((o ^ (j & 15)) << 3)] =
        *(const short8*)&Wg_bf[oi << 3];
  }
  if (t < 128) { br_l[t] = br[t]; bg_l[t] = bg[t]; }
  __syncthreads();

  const int wid  = t >> 6;
  const int lane = t & 63;
  const int lrow = lane & 15;   // A/B fragment: row/col index
  const int lgrp = lane >> 4;   // k-octet group
  const int m0 = blockIdx.x * 128 + wid * 16;
  if (m0 >= n) return;
  unsigned short* tw = t_l[wid];

  const int mr = m0 + lrow;
  const bool rowok = mr < n;

  // A-fragments of mean: direct 16B global bf16 loads
  short8 am[4];
  #pragma unroll
  for (int ks = 0; ks < 4; ++ks) {
    short8 v = {0, 0, 0, 0, 0, 0, 0, 0};
    if (rowok)
      v = *(const short8*)&mean_bf[(size_t)mr * DD + ks * 32 + lgrp * 8];
    am[ks] = v;
  }

  // t = mean @ Wr^T + br
  f32x4 tac[8];
  #pragma unroll
  for (int jt = 0; jt < 8; ++jt) {
    float bv = br_l[jt * 16 + lrow];
    f32x4 c = {bv, bv, bv, bv};
    #pragma unroll
    for (int ks = 0; ks < 4; ++ks) {
      int o = ks * 4 + lgrp;
      short8 b = *(short8*)&Wr_l[(jt * 16 + lrow) * 128 + ((o ^ lrow) << 3)];
      c = __builtin_amdgcn_mfma_f32_16x16x32_bf16(am[ks], b, c, 0, 0, 0);
    }
    tac[jt] = c;
  }

  // cnt==0 -> t = 0 (reference: mean_msg exactly 0)
  const int rbase = m0 + lgrp * 4;
  #pragma unroll
  for (int r = 0; r < 4; ++r) {
    int rr = rbase + r;
    int cv = (rr < n) ? cnt[rr] : 0;
    if (cv == 0) {
      #pragma unroll
      for (int jt = 0; jt < 8; ++jt) tac[jt][r] = 0.f;
    }
  }

  // relayout t: C/D layout -> per-wave LDS patch (bf16, octet-swizzled)
  #pragma unroll
  for (int jt = 0; jt < 8; ++jt) {
    int col = jt * 16 + lrow;
    int oc = col >> 3, ci = col & 7;
    #pragma unroll
    for (int r = 0; r < 4; ++r) {
      int rr4 = lgrp * 4 + r;
      tw[rr4 * DD + ((oc ^ rr4) << 3) + ci] = f2bf(tac[jt][r]);
    }
  }

  // A-fragments of row: direct 16B global bf16 loads
  short8 ar[4];
  #pragma unroll
  for (int ks = 0; ks < 4; ++ks) {
    short8 v = {0, 0, 0, 0, 0, 0, 0, 0};
    if (rowok)
      v = *(const short8*)&rows16[(size_t)mr * DD + ks * 32 + lgrp * 8];
    ar[ks] = v;
  }

  // A-fragments of t (from the per-wave patch; same-wave RAW)
  short8 at[4];
  #pragma unroll
  for (int ks = 0; ks < 4; ++ks) {
    int o = ks * 4 + lgrp;
    at[ks] = *(short8*)&tw[lrow * DD + ((o ^ lrow) << 3)];
  }

  // gate GEMM (K=256) + blend + store
  #pragma unroll
  for (int jt = 0; jt < 8; ++jt) {
    float bv = bg_l[jt * 16 + lrow];
    f32x4 c = {bv, bv, bv, bv};
    #pragma unroll
    for (int ks = 0; ks < 4; ++ks) {
      int o = ks * 4 + lgrp;
      short8 b = *(short8*)&Wg_l[(jt * 16 + lrow) * 256 + ((o ^ lrow) << 3)];
      c = __builtin_amdgcn_mfma_f32_16x16x32_bf16(ar[ks], b, c, 0, 0, 0);
    }
    #pragma unroll
    for (int ks = 0; ks < 4; ++ks) {
      int o = (ks + 4) * 4 + lgrp;
      short8 b = *(short8*)&Wg_l[(jt * 16 + lrow) * 256 + ((o ^ lrow) << 3)];
      c = __builtin_amdgcn_mfma_f32_16x16x32_bf16(at[ks], b, c, 0, 0, 0);
    }
    int col = jt * 16 + lrow;
    #pragma unroll
    for (int r = 0; r < 4; ++r) {
      int rr = rbase + r;
      if (rr < n) {
        float g = 1.f / (1.f + __expf(-c[r]));
        float rowf = b2f(rows16[(size_t)rr * DD + col]);
        out[(size_t)rr * DD + col] = g * rowf + (1.f - g) * tac[jt][r];
      }
    }
  }
}

extern "C" void kernel_launch(void* const* d_in, const int* in_sizes, int n_in,
                              void* d_out, int out_size, void* d_ws, size_t ws_size,
                              hipStream_t stream) {
  const float* A      = (const float*)d_in[0];
  const float* B      = (const float*)d_in[1];
  const float* W_fwd  = (const float*)d_in[2];
  const float* b_fwd  = (const float*)d_in[3];
  const float* W_rev  = (const float*)d_in[4];
  const float* b_rev  = (const float*)d_in[5];
  const float* W_gate = (const float*)d_in[6];
  const float* b_gate = (const float*)d_in[7];
  const int*   src    = (const int*)d_in[8];
  const int*   dst    = (const int*)d_in[9];

  const int n_a = in_sizes[0] / DD;
  const int n_b = in_sizes[1] / DD;
  const int E   = in_sizes[8];
  const int n_total = n_a + n_b;

  const int na_bins = (n_a + 1023) >> 10;     // A: 1024 rows/bin (deg ~5)
  const int nb_bins = (n_b + 255) >> 8;       // B: 256 rows/bin (deg ~20)
  const int nbins   = na_bins + nb_bins;      // ~392 (<= 512)

  float* out = (float*)d_out;

  // workspace layout (ints) — cnt and binraw adjacent for one memset
  int* cnt      = (int*)d_ws;                        // [n_total]
  int* binraw   = cnt + n_total;                     // [1024]
  int* start    = binraw + 1024;                     // [n_total]
  int* cursor   = start + n_total;                   // [n_total]
  int* partials = cursor + n_total;                  // [1024]
  int* binstart = partials + 1024;                   // [1024]
  int* bincur   = binstart + 1024;                   // [1024]
  uint2* binrec = (uint2*)(bincur + 1024);           // [2E] records (16 MB)
  int* partner  = (int*)(binrec + 2 * (size_t)E);    // [2E]
  uintptr_t wp = (uintptr_t)(partner + 2 * (size_t)E);
  wp = (wp + 63) & ~(uintptr_t)63;
  unsigned short* wbf = (unsigned short*)wp;         // [65536] bf16 weights
  unsigned short* rows_bf = wbf + 65536;             // [n_total*128] bf16 rows
  unsigned short* A_bf = rows_bf;
  unsigned short* B_bf = rows_bf + (size_t)n_a * DD;
  unsigned short* mean_bf = rows_bf + (size_t)n_total * DD;  // [n_total*128]

  const int nch  = (n_total + SCHUNK - 1) / SCHUNK;
  const int eblk = (E + 255) / 256;
  const int nA4  = n_a * (DD / 4);
  const int nt4  = n_total * (DD / 4);

  hipMemsetAsync(cnt, 0, ((size_t)n_total + 1024) * sizeof(int), stream);

  rowconv_kernel<<<2048, 256, 0, stream>>>(A, B, rows_bf, nA4, nt4);
  wconv_kernel<<<256, 256, 0, stream>>>(W_rev, W_fwd, W_gate, wbf);

  hist_kernel<<<eblk, 256, 0, stream>>>(src, dst, cnt, n_a, E);
  scan1_kernel<<<nch, 256, 0, stream>>>(cnt, n_total, partials);
  scan2_kernel<<<1, 256, 0, stream>>>(partials, nch);
  scan3_kernel<<<nch, 256, 0, stream>>>(cnt, n_total, partials, start, cursor);

  // binned scatter: hist -> scan -> fill (dense per-CU runs) -> fine scatter
  binhist_kernel<<<1024, 256, 0, stream>>>(src, dst, binraw, na_bins, nbins, E);
  binscan_kernel<<<1, 512, 0, stream>>>(binraw, nbins, binstart, bincur);
  binfill_kernel<<<(E + 4095) / 4096, 512, 0, stream>>>(
      src, dst, bincur, binrec, n_a, na_bins, nbins, E);
  binscatter_kernel<<<nbins, 256, 0, stream>>>(
      binrec, binstart, bincur, cursor, partner);

  aggregate_mean_bf16_kernel<<<(n_total + 3) / 4, 256, 0, stream>>>(
      A_bf, B_bf, partner, start, cnt, mean_bf, n_a, n_total);

  // A range: t = mean_a @ W_rev^T + b_rev
  fused_post_kernel<<<(n_a + 127) / 128, 512, 0, stream>>>(
      A_bf, mean_bf, cnt, wbf, wbf + 32768, b_rev, b_gate, out, n_a);
  // B range: t = mean_b @ W_fwd^T + b_fwd
  fused_post_kernel<<<(n_b + 127) / 128, 512, 0, stream>>>(
      B_bf, mean_bf + (size_t)n_a * DD, cnt + n_a, wbf + 16384, wbf + 32768,
      b_fwd, b_gate, out + (size_t)n_a * DD, n_b);
}